// Round 10
// baseline (144.485 us; speedup 1.0000x reference)
//
#include <hip/hip_runtime.h>
#include <math.h>

#define Bn 16
#define Cn 256
#define Ln 16384
#define Mn 64
#define LN_EPS 1e-5f
#define CHUNK 32
#define NSUB 8
#define NCHB (Ln / (CHUNK * NSUB))   // 64 chunk-groups per batch
#define XSTR 33                      // LDS row stride: <=2-way bank aliasing (free)

typedef float v4f __attribute__((ext_vector_type(4)));

// K1: persistent fused logits+softmax+pooling. Each block: 8 chunks of 32 l,
// double-buffered LDS, register prefetch one chunk ahead, register flash-accum.
// grid (NCHB, Bn) = 1024 blocks, 256 thr, ~73 KB LDS -> 2 blocks/CU.
__global__ __launch_bounds__(256) void k_pool(
        const float* __restrict__ x, const float* __restrict__ w_mask,
        const float* __restrict__ b_mask,
        float* __restrict__ ctxU,   // [Bn][NCHB][Cn]
        float* __restrict__ mz) {   // [Bn][NCHB][2]
    const int blk = blockIdx.x, b = blockIdx.y;
    const int t = threadIdx.x;           // 256
    const int c0 = t >> 3, f4 = t & 7;   // staging: channel group / l-quad
    __shared__ float xs[2][Cn * XSTR];   // 2 x 33792 B
    __shared__ float wm_s[Cn];
    __shared__ float redA[32 * 32];      // [c0][l] : logit partials
    __shared__ float e_s[CHUNK];
    __shared__ float mzs[2];             // (m_new, z_chunk)

    wm_s[t] = w_mask[t];

    // row pointers for this thread's 8 staged channels
    const size_t xrow = (size_t)b * Cn * Ln + (size_t)blk * (CHUNK * NSUB);
    const float* xc[8];
    #pragma unroll
    for (int r = 0; r < 8; ++r)
        xc[r] = x + xrow + (size_t)(r * 32 + c0) * Ln + 4 * f4;

    // prologue: load chunk 0 into regs
    float4 r0[8], r1[8];
    #pragma unroll
    for (int r = 0; r < 8; ++r) r0[r] = *(const float4*)(xc[r]);
    __syncthreads();                    // wm_s ready
    float wm_r[8];
    #pragma unroll
    for (int r = 0; r < 8; ++r) wm_r[r] = wm_s[r * 32 + c0];
    const float bm = b_mask[0];

    float acc = 0.f, m_run = -1e30f, z_run = 0.f;

    #pragma unroll
    for (int k = 0; k < NSUB; ++k) {
        float4* cur = (k & 1) ? r1 : r0;
        float4* nxt = (k & 1) ? r0 : r1;
        // a) prefetch next chunk (loads issued before any dependent use)
        if (k < NSUB - 1) {
            #pragma unroll
            for (int r = 0; r < 8; ++r)
                nxt[r] = *(const float4*)(xc[r] + (k + 1) * CHUNK);
        }
        // b) logit partials from regs + stage to LDS
        float4 p = {0.f, 0.f, 0.f, 0.f};
        #pragma unroll
        for (int r = 0; r < 8; ++r) {
            float4 v = cur[r];
            const float w = wm_r[r];
            p.x += v.x * w; p.y += v.y * w; p.z += v.z * w; p.w += v.w * w;
            float* dst = &xs[k & 1][(r * 32 + c0) * XSTR + 4 * f4];
            dst[0] = v.x; dst[1] = v.y; dst[2] = v.z; dst[3] = v.w;
        }
        *(float4*)&redA[c0 * 32 + 4 * f4] = p;   // addr = 4t: conflict-free
        __syncthreads();
        // c) finalize 32 logits, chunk max/exp/sum (lanes 0..31 of wave 0)
        if (t < 32) {
            float logit = bm;
            #pragma unroll 8
            for (int i = 0; i < 32; ++i) logit += redA[i * 32 + t];
            float mc = logit;
            for (int off = 16; off; off >>= 1) mc = fmaxf(mc, __shfl_xor(mc, off, 32));
            const float mn = fmaxf(m_run, mc);
            const float e = expf(logit - mn);
            e_s[t] = e;
            float z = e;
            for (int off = 16; off; off >>= 1) z += __shfl_xor(z, off, 32);
            if (t == 0) { mzs[0] = mn; mzs[1] = z; }
        }
        __syncthreads();
        // d) pooled accumulate: thread t = channel t; flash rescale
        const float mn = mzs[0], zc = mzs[1];
        const float sa = expf(m_run - mn);
        float s = 0.f;
        #pragma unroll 8
        for (int l = 0; l < CHUNK; ++l)
            s += xs[k & 1][t * XSTR + l] * e_s[l];
        acc = acc * sa + s;
        z_run = z_run * sa + zc;
        m_run = mn;
    }

    ctxU[((size_t)b * NCHB + blk) * Cn + t] = acc;
    if (t == 0) {
        mz[(b * NCHB + blk) * 2 + 0] = m_run;
        mz[(b * NCHB + blk) * 2 + 1] = z_run;
    }
}

// K2: ctx[b][c] = sum_g ctxU[b][g][c] * exp(m_g - M)/Z. grid (16, Bn), 256 thr.
__global__ void k_ctx(const float* __restrict__ ctxU, const float* __restrict__ mz,
                      float* __restrict__ ctx) {
    const int cblk = blockIdx.x, b = blockIdx.y;
    const int t = threadIdx.x;   // 256
    __shared__ float sc_s[NCHB];
    __shared__ float red[256];

    if (t < NCHB) {              // 64 = one wave
        const float mt = mz[(b * NCHB + t) * 2];
        const float zt = mz[(b * NCHB + t) * 2 + 1];
        float M = mt;
        for (int off = 32; off; off >>= 1) M = fmaxf(M, __shfl_xor(M, off, 64));
        float zw = zt * expf(mt - M);
        for (int off = 32; off; off >>= 1) zw += __shfl_xor(zw, off, 64);
        sc_s[t] = expf(mt - M) / zw;
    }
    __syncthreads();

    const int cl = t & 15, g = t >> 4;   // 16 groups x 4 chunks
    const int c = cblk * 16 + cl;
    float p = 0.f;
    #pragma unroll
    for (int j = 0; j < 4; ++j) {
        const int chk = g * 4 + j;
        p += ctxU[((size_t)b * NCHB + chk) * Cn + c] * sc_s[chk];
    }
    red[g * 16 + cl] = p;
    __syncthreads();
    if (t < 16) {
        float s = 0.f;
        #pragma unroll
        for (int j = 0; j < 16; ++j) s += red[j * 16 + t];
        ctx[b * Cn + cblk * 16 + t] = s;
    }
}

// K3: tiny MLP on normalized ctx. grid Bn, 256 thr.
__global__ void k_mlp(const float* __restrict__ ctx, const float* __restrict__ w1,
                      const float* __restrict__ b1, const float* __restrict__ ln_g,
                      const float* __restrict__ ln_b, const float* __restrict__ w2,
                      const float* __restrict__ b2, float* __restrict__ add) {
    const int b = blockIdx.x;
    const int t = threadIdx.x;   // 256
    __shared__ float ctx_s[Cn];
    __shared__ float h_s[Mn];
    ctx_s[t] = ctx[b * Cn + t];
    __syncthreads();

    const int m4 = t >> 2, j = t & 3;
    float hp = 0.f;
    for (int c = j; c < Cn; c += 4) hp += ctx_s[c] * w1[m4 * Cn + c];
    hp += __shfl_xor(hp, 1, 64);
    hp += __shfl_xor(hp, 2, 64);
    if (j == 0) h_s[m4] = hp + b1[m4];
    __syncthreads();

    if (t < 64) {
        float h = h_s[t];
        float mu = h;
        for (int off = 32; off; off >>= 1) mu += __shfl_xor(mu, off, 64);
        mu *= (1.f / 64.f);
        const float d = h - mu;
        float var = d * d;
        for (int off = 32; off; off >>= 1) var += __shfl_xor(var, off, 64);
        var *= (1.f / 64.f);
        h = d * rsqrtf(var + LN_EPS) * ln_g[t] + ln_b[t];
        h_s[t] = fmaxf(h, 0.f);
    }
    __syncthreads();

    float a = b2[t];
    #pragma unroll
    for (int mm = 0; mm < Mn; ++mm) a += h_s[mm] * w2[t * Mn + mm];
    add[b * Cn + t] = a;
}

// K4: out = x + add broadcast. Nontemporal stores. grid (4, Bn*Cn), 256 thr.
__global__ void k_out(const float* __restrict__ x, const float* __restrict__ add,
                      float* __restrict__ out) {
    const int bc = blockIdx.y;
    const float a = add[bc];
    const size_t base = (size_t)bc * Ln + (size_t)blockIdx.x * 4096;
    const float4* xi = (const float4*)(x + base);
    v4f* xo = (v4f*)(out + base);
    const int t = threadIdx.x;
    #pragma unroll
    for (int k = 0; k < 4; ++k) {
        float4 v = xi[k * 256 + t];
        v4f o = {v.x + a, v.y + a, v.z + a, v.w + a};
        __builtin_nontemporal_store(o, xo + k * 256 + t);
    }
}

extern "C" void kernel_launch(void* const* d_in, const int* in_sizes, int n_in,
                              void* d_out, int out_size, void* d_ws, size_t ws_size,
                              hipStream_t stream) {
    const float* x      = (const float*)d_in[0];
    const float* w_mask = (const float*)d_in[1];
    const float* b_mask = (const float*)d_in[2];
    const float* w1     = (const float*)d_in[3];
    const float* b1     = (const float*)d_in[4];
    const float* ln_g   = (const float*)d_in[5];
    const float* ln_b   = (const float*)d_in[6];
    const float* w2     = (const float*)d_in[7];
    const float* b2     = (const float*)d_in[8];
    float* out = (float*)d_out;

    float* ws   = (float*)d_ws;
    float* ctxU = ws;                                  // Bn*NCHB*Cn = 262144 floats (1 MiB)
    float* mz   = ctxU + (size_t)Bn * NCHB * Cn;       // Bn*NCHB*2 = 2048 floats
    float* ctx  = mz + (size_t)Bn * NCHB * 2;          // Bn*Cn = 4096 floats
    float* add  = ctx + (size_t)Bn * Cn;               // Bn*Cn = 4096 floats

    k_pool<<<dim3(NCHB, Bn), 256, 0, stream>>>(x, w_mask, b_mask, ctxU, mz);
    k_ctx<<<dim3(Cn / 16, Bn), 256, 0, stream>>>(ctxU, mz, ctx);
    k_mlp<<<Bn, 256, 0, stream>>>(ctx, w1, b1, ln_g, ln_b, w2, b2, add);
    k_out<<<dim3(4, Bn * Cn), 256, 0, stream>>>(x, add, out);
}